// Round 1
// baseline (23927.090 us; speedup 1.0000x reference)
//
#include <hip/hip_runtime.h>

// ---------------------------------------------------------------------------
// LSTM autoregressive: B=8192, T_H=128, T_F=125, H=128, MOTION_DIM=6.
// Round 1: correct fp32-VALU baseline. Persistent per-block state over all
// 253 timesteps; BM=16 rows/block, 512 blocks, 256 threads (4 waves).
// Weights pre-transposed+packed into d_ws by setup kernel.
// ---------------------------------------------------------------------------

#define BM 16
#define HSTR 132   // row stride for h/o1 LDS tiles (keeps float2 aligned, breaks bank patterns)

// ws layout (floats)
#define OFF_EWT0 0        // [134][512]
#define OFF_EWT1 68608    // [256][512]
#define OFF_DWT0 199680   // [130][512]
#define OFF_DWT1 266240   // [256][512]
#define OFF_W1T  397312   // [128][128]
#define OFF_W2T  413696   // [128][2]
#define OFF_EB0  413952
#define OFF_EB1  414464
#define OFF_DB0  414976
#define OFF_DB1  415488
#define OFF_B1   416000
#define OFF_B2   416128
#define WS_FLOATS 416130

__device__ __forceinline__ float fsig(float x) {
    return 1.0f / (1.0f + __expf(-x));
}
__device__ __forceinline__ float ftanh(float x) {
    float a = fabsf(x);
    float e = __expf(-2.0f * a);          // in (0,1], never overflows
    float t = (1.0f - e) / (1.0f + e);
    return x < 0.0f ? -t : t;
}

// C[16][512] += X[16][K] * Wt[K][512]; thread owns 4 rows x (2 units x 4 gate-blocks).
template<int K, int LDX>
__device__ __forceinline__ void gemm_acc(float acc[4][2][4],
    const float* __restrict__ Wt, const float* __restrict__ X, int u2, int r0)
{
    const float* xp0 = X + (r0 + 0) * LDX;
    const float* xp1 = X + (r0 + 1) * LDX;
    const float* xp2 = X + (r0 + 2) * LDX;
    const float* xp3 = X + (r0 + 3) * LDX;
    const float* wp = Wt + u2;
    #pragma unroll 2
    for (int k = 0; k < K; ++k) {
        float xr[4];
        xr[0] = xp0[k]; xr[1] = xp1[k]; xr[2] = xp2[k]; xr[3] = xp3[k];
        float2 w0 = *(const float2*)(wp);
        float2 w1 = *(const float2*)(wp + 128);
        float2 w2 = *(const float2*)(wp + 256);
        float2 w3 = *(const float2*)(wp + 384);
        wp += 512;
        float wv[4][2] = {{w0.x, w0.y}, {w1.x, w1.y}, {w2.x, w2.y}, {w3.x, w3.y}};
        #pragma unroll
        for (int gi = 0; gi < 4; ++gi)
            #pragma unroll
            for (int ui = 0; ui < 2; ++ui)
                #pragma unroll
                for (int ri = 0; ri < 4; ++ri)
                    acc[gi][ui][ri] = fmaf(wv[gi][ui], xr[ri], acc[gi][ui][ri]);
    }
}

// head layer-1 GEMM: [16][128] += X[16][128] * W1t[128][128]
__device__ __forceinline__ void gemm_head(float hacc[2][4],
    const float* __restrict__ W1t, const float* __restrict__ X, int u2, int r0)
{
    const float* xp0 = X + (r0 + 0) * HSTR;
    const float* xp1 = X + (r0 + 1) * HSTR;
    const float* xp2 = X + (r0 + 2) * HSTR;
    const float* xp3 = X + (r0 + 3) * HSTR;
    const float* wp = W1t + u2;
    #pragma unroll 2
    for (int k = 0; k < 128; ++k) {
        float2 w = *(const float2*)(wp);
        wp += 128;
        float xr[4];
        xr[0] = xp0[k]; xr[1] = xp1[k]; xr[2] = xp2[k]; xr[3] = xp3[k];
        #pragma unroll
        for (int ri = 0; ri < 4; ++ri) {
            hacc[0][ri] = fmaf(w.x, xr[ri], hacc[0][ri]);
            hacc[1][ri] = fmaf(w.y, xr[ri], hacc[1][ri]);
        }
    }
}

__device__ __forceinline__ void lstm_update(float acc[4][2][4],
    const float* __restrict__ bias, float c[2][4], float* __restrict__ ht,
    int u2, int r0)
{
    float bi0 = bias[u2],       bi1 = bias[u2 + 1];
    float bf0 = bias[128 + u2], bf1 = bias[128 + u2 + 1];
    float bg0 = bias[256 + u2], bg1 = bias[256 + u2 + 1];
    float bo0 = bias[384 + u2], bo1 = bias[384 + u2 + 1];
    #pragma unroll
    for (int ri = 0; ri < 4; ++ri) {
        float iv0 = fsig(acc[0][0][ri] + bi0);
        float fv0 = fsig(acc[1][0][ri] + bf0);
        float gv0 = ftanh(acc[2][0][ri] + bg0);
        float ov0 = fsig(acc[3][0][ri] + bo0);
        float cn0 = fv0 * c[0][ri] + iv0 * gv0;
        c[0][ri] = cn0;
        float h0 = ov0 * ftanh(cn0);

        float iv1 = fsig(acc[0][1][ri] + bi1);
        float fv1 = fsig(acc[1][1][ri] + bf1);
        float gv1 = ftanh(acc[2][1][ri] + bg1);
        float ov1 = fsig(acc[3][1][ri] + bo1);
        float cn1 = fv1 * c[1][ri] + iv1 * gv1;
        c[1][ri] = cn1;
        float h1 = ov1 * ftanh(cn1);

        *(float2*)(ht + (r0 + ri) * HSTR + u2) = make_float2(h0, h1);
    }
}

__global__ void __launch_bounds__(256, 2)
lstm_main(const float* __restrict__ hist, const float* __restrict__ ws,
          float* __restrict__ out)
{
    const float* encWt0 = ws + OFF_EWT0;
    const float* encWt1 = ws + OFF_EWT1;
    const float* decWt0 = ws + OFF_DWT0;
    const float* decWt1 = ws + OFF_DWT1;
    const float* W1t    = ws + OFF_W1T;
    const float* W2t    = ws + OFF_W2T;
    const float* encB0  = ws + OFF_EB0;
    const float* encB1  = ws + OFF_EB1;
    const float* decB0  = ws + OFF_DB0;
    const float* decB1  = ws + OFF_DB1;
    const float* b1c    = ws + OFF_B1;
    const float* b2c    = ws + OFF_B2;

    __shared__ float h0t[BM * HSTR];
    __shared__ float h1t[BM * HSTR];
    __shared__ float o1t[BM * HSTR];
    __shared__ float xt[BM * 8];

    const int tid = threadIdx.x;
    const int ul = tid & 63;
    const int u2 = ul * 2;
    const int rq = tid >> 6;
    const int r0 = rq * 4;
    const int b0 = blockIdx.x * BM;

    for (int i = tid; i < BM * HSTR; i += 256) { h0t[i] = 0.0f; h1t[i] = 0.0f; }
    float c0[2][4] = {{0,0,0,0},{0,0,0,0}};
    float c1[2][4] = {{0,0,0,0},{0,0,0,0}};

    const int lr = tid / 6;           // hist loader row (tid < 96)
    const int ld = tid - lr * 6;      // hist loader dim
    __syncthreads();

    // ---------------- encoder: 128 steps ----------------
    for (int t = 0; t < 128; ++t) {
        if (tid < 96) xt[lr * 8 + ld] = hist[(b0 + lr) * 768 + t * 6 + ld];
        __syncthreads();

        float acc[4][2][4] = {};
        gemm_acc<6, 8>(acc, encWt0, xt, u2, r0);
        gemm_acc<128, HSTR>(acc, encWt0 + 6 * 512, h0t, u2, r0);
        __syncthreads();
        lstm_update(acc, encB0, c0, h0t, u2, r0);
        __syncthreads();

        float acc2[4][2][4] = {};
        gemm_acc<128, HSTR>(acc2, encWt1, h0t, u2, r0);
        gemm_acc<128, HSTR>(acc2, encWt1 + 128 * 512, h1t, u2, r0);
        __syncthreads();
        lstm_update(acc2, encB1, c1, h1t, u2, r0);
        __syncthreads();
    }

    // seed decoder input with last_pos = hist[:, -1, :2]
    if (tid < 32) {
        int r = tid >> 1, j = tid & 1;
        xt[r * 8 + j] = hist[(b0 + r) * 768 + 762 + j];
    }
    __syncthreads();

    // ---------------- decoder: 125 steps ----------------
    for (int t = 0; t < 125; ++t) {
        float acc[4][2][4] = {};
        gemm_acc<2, 8>(acc, decWt0, xt, u2, r0);
        gemm_acc<128, HSTR>(acc, decWt0 + 2 * 512, h0t, u2, r0);
        __syncthreads();
        lstm_update(acc, decB0, c0, h0t, u2, r0);
        __syncthreads();

        float acc2[4][2][4] = {};
        gemm_acc<128, HSTR>(acc2, decWt1, h0t, u2, r0);
        gemm_acc<128, HSTR>(acc2, decWt1 + 128 * 512, h1t, u2, r0);
        __syncthreads();
        lstm_update(acc2, decB1, c1, h1t, u2, r0);
        __syncthreads();

        // head layer 1: relu(h1 @ W1^T + b1) -> o1t
        float hacc[2][4] = {};
        gemm_head(hacc, W1t, h1t, u2, r0);
        float bu0 = b1c[u2], bu1 = b1c[u2 + 1];
        #pragma unroll
        for (int ri = 0; ri < 4; ++ri) {
            float v0 = hacc[0][ri] + bu0; v0 = v0 > 0.0f ? v0 : 0.0f;
            float v1 = hacc[1][ri] + bu1; v1 = v1 > 0.0f ? v1 : 0.0f;
            *(float2*)(o1t + (r0 + ri) * HSTR + u2) = make_float2(v0, v1);
        }
        __syncthreads();

        // head layer 2: pred = o1 @ W2^T + b2; write output + next x
        if (tid < 32) {
            int r = tid >> 1, j = tid & 1;
            const float* op = o1t + r * HSTR;
            const float* w2 = W2t + j;
            float s0 = 0.f, s1 = 0.f, s2 = 0.f, s3 = 0.f;
            #pragma unroll
            for (int k = 0; k < 128; k += 4) {
                s0 = fmaf(op[k],     w2[2 * k],     s0);
                s1 = fmaf(op[k + 1], w2[2 * k + 2], s1);
                s2 = fmaf(op[k + 2], w2[2 * k + 4], s2);
                s3 = fmaf(op[k + 3], w2[2 * k + 6], s3);
            }
            float pred = b2c[j] + ((s0 + s1) + (s2 + s3));
            out[(b0 + r) * 250 + t * 2 + j] = pred;
            xt[r * 8 + j] = pred;
        }
        __syncthreads();
    }
}

// ---------------------------------------------------------------------------
// setup: transpose + pack weights, fuse bias pairs
// ---------------------------------------------------------------------------
__global__ void setup_kernel(
    const float* __restrict__ eWih0, const float* __restrict__ eWhh0,
    const float* __restrict__ ebih0, const float* __restrict__ ebhh0,
    const float* __restrict__ eWih1, const float* __restrict__ eWhh1,
    const float* __restrict__ ebih1, const float* __restrict__ ebhh1,
    const float* __restrict__ dWih0, const float* __restrict__ dWhh0,
    const float* __restrict__ dbih0, const float* __restrict__ dbhh0,
    const float* __restrict__ dWih1, const float* __restrict__ dWhh1,
    const float* __restrict__ dbih1, const float* __restrict__ dbhh1,
    const float* __restrict__ W1, const float* __restrict__ b1,
    const float* __restrict__ W2, const float* __restrict__ b2,
    float* __restrict__ ws)
{
    int i = blockIdx.x * 256 + threadIdx.x;
    if (i >= WS_FLOATS) return;
    if (i < OFF_EWT1) {                       // encWt0 [134][512]
        int k = i >> 9, g = i & 511;
        ws[i] = (k < 6) ? eWih0[g * 6 + k] : eWhh0[g * 128 + (k - 6)];
    } else if (i < OFF_DWT0) {                // encWt1 [256][512]
        int j = i - OFF_EWT1; int k = j >> 9, g = j & 511;
        ws[i] = (k < 128) ? eWih1[g * 128 + k] : eWhh1[g * 128 + (k - 128)];
    } else if (i < OFF_DWT1) {                // decWt0 [130][512]
        int j = i - OFF_DWT0; int k = j >> 9, g = j & 511;
        ws[i] = (k < 2) ? dWih0[g * 2 + k] : dWhh0[g * 128 + (k - 2)];
    } else if (i < OFF_W1T) {                 // decWt1 [256][512]
        int j = i - OFF_DWT1; int k = j >> 9, g = j & 511;
        ws[i] = (k < 128) ? dWih1[g * 128 + k] : dWhh1[g * 128 + (k - 128)];
    } else if (i < OFF_W2T) {                 // W1t [128][128]
        int j = i - OFF_W1T; int k = j >> 7, u = j & 127;
        ws[i] = W1[u * 128 + k];
    } else if (i < OFF_EB0) {                 // W2t [128][2]
        int j = i - OFF_W2T; int k = j >> 1, o = j & 1;
        ws[i] = W2[o * 128 + k];
    } else if (i < OFF_EB1) { int j = i - OFF_EB0; ws[i] = ebih0[j] + ebhh0[j]; }
    else if (i < OFF_DB0)   { int j = i - OFF_EB1; ws[i] = ebih1[j] + ebhh1[j]; }
    else if (i < OFF_DB1)   { int j = i - OFF_DB0; ws[i] = dbih0[j] + dbhh0[j]; }
    else if (i < OFF_B1)    { int j = i - OFF_DB1; ws[i] = dbih1[j] + dbhh1[j]; }
    else if (i < OFF_B2)    { ws[i] = b1[i - OFF_B1]; }
    else                    { ws[i] = b2[i - OFF_B2]; }
}

extern "C" void kernel_launch(void* const* d_in, const int* in_sizes, int n_in,
                              void* d_out, int out_size, void* d_ws, size_t ws_size,
                              hipStream_t stream)
{
    const float* hist = (const float*)d_in[0];
    float* ws = (float*)d_ws;

    setup_kernel<<<(WS_FLOATS + 255) / 256, 256, 0, stream>>>(
        (const float*)d_in[1],  (const float*)d_in[2],
        (const float*)d_in[3],  (const float*)d_in[4],
        (const float*)d_in[5],  (const float*)d_in[6],
        (const float*)d_in[7],  (const float*)d_in[8],
        (const float*)d_in[9],  (const float*)d_in[10],
        (const float*)d_in[11], (const float*)d_in[12],
        (const float*)d_in[13], (const float*)d_in[14],
        (const float*)d_in[15], (const float*)d_in[16],
        (const float*)d_in[17], (const float*)d_in[18],
        (const float*)d_in[19], (const float*)d_in[20],
        ws);

    lstm_main<<<512, 256, 0, stream>>>(hist, ws, (float*)d_out);
}

// Round 2
// 10232.117 us; speedup vs baseline: 2.3384x; 2.3384x over previous
//
#include <hip/hip_runtime.h>

// ---------------------------------------------------------------------------
// LSTM autoregressive, MI355X. Round 2: fp16 hi/lo split MFMA (16x16x32_f16).
// B=8192, BM=32 rows/block, 256 blocks, 512 threads (8 waves; wave w owns
// 64 gate-cols = 16 units). Weights prepacked into per-lane MFMA fragment
// order by setup kernel. lo-planes prescaled x2048 (subnormal-safe), second
// accumulator folded back as acc += acc2/2048.
// ---------------------------------------------------------------------------

typedef _Float16 f16;
typedef _Float16 f16x4 __attribute__((ext_vector_type(4)));
typedef _Float16 f16x8 __attribute__((ext_vector_type(8)));
typedef float    f32x4 __attribute__((ext_vector_type(4)));

#define MFMA16(a,b,c) __builtin_amdgcn_mfma_f32_16x16x32_f16((a),(b),(c),0,0,0)

// ws layout: fp16 fragment region (halves), then fp32 region (floats)
#define HOFF_E0 0        // enc L0: KT=5  (k: [Whh 128 | Wih 6 | pad])
#define HOFF_E1 163840   // enc L1: KT=8  (k: [Wih 128 | Whh 128])
#define HOFF_D0 425984   // dec L0: KT=5  (k: [Whh 128 | Wih 2 | pad])
#define HOFF_D1 589824   // dec L1: KT=8
#define HOFF_H  851968   // head W1: KT=4, NT=8
#define H_TOTAL 884736
#define FOFF    442368   // float offset of fp32 region (= H_TOTAL/2)
#define FB_E0 0
#define FB_E1 512
#define FB_D0 1024
#define FB_D1 1536
#define FB_H1 2048
#define FB_W2 2176
#define FB_B2 2432
#define F_TOTAL 2434

#define LO_SCALE 2048.0f
#define LO_INV   (1.0f/2048.0f)

#define A1S 168   // A1 row stride (halves): 160 k + 8 pad
#define A2S 136   // A2 row stride (halves): 128 k + 8 pad

__device__ __forceinline__ float fsig(float x){ return 1.0f/(1.0f+__expf(-x)); }
__device__ __forceinline__ float ftanh(float x){
  float a = fabsf(x);
  float e = __expf(-2.0f*a);
  float t = (1.0f-e)/(1.0f+e);
  return x < 0.0f ? -t : t;
}

// A fragment: row = mt*16 + (lane&15); k = kc + (lane>>4)*4 + j (+16 for j>=4)
template<int STRIDE>
__device__ __forceinline__ f16x8 load_afrag(const f16* buf, int mt, int kc, int lane){
  const f16* p = buf + (mt*16 + (lane&15))*STRIDE + kc + ((lane>>4)<<2);
  f16x4 lo = *(const f16x4*)p;
  f16x4 hi = *(const f16x4*)(p+16);
  return __builtin_shufflevector(lo, hi, 0,1,2,3,4,5,6,7);
}

// B fragments for 4 ntiles x {hi,lo}: one dwordx4 per lane per (tile,plane)
__device__ __forceinline__ void load_b4(f16x8* dst, const f16x8* __restrict__ Bp,
                                        int kt, int nbase, int lane){
#pragma unroll
  for (int i=0;i<4;++i){
    int base = ((kt*32 + nbase + i)*2)*64 + lane;
    dst[2*i]   = Bp[base];        // hi plane
    dst[2*i+1] = Bp[base+64];     // lo plane (prescaled x2048)
  }
}

template<int SPLIT>
__device__ __forceinline__ void load_a4(f16x8* dst, const f16* A1h, const f16* A1l,
                                        const f16* A2h, const f16* A2l, int kt, int lane){
  if (kt < SPLIT){
    int kc = kt*32;
    dst[0]=load_afrag<A1S>(A1h,0,kc,lane);
    dst[1]=load_afrag<A1S>(A1l,0,kc,lane);
    dst[2]=load_afrag<A1S>(A1h,1,kc,lane);
    dst[3]=load_afrag<A1S>(A1l,1,kc,lane);
  } else {
    int kc = (kt-SPLIT)*32;
    dst[0]=load_afrag<A2S>(A2h,0,kc,lane);
    dst[1]=load_afrag<A2S>(A2l,0,kc,lane);
    dst[2]=load_afrag<A2S>(A2h,1,kc,lane);
    dst[3]=load_afrag<A2S>(A2l,1,kc,lane);
  }
}

__device__ __forceinline__ void init_acc(f32x4 acc[2][4], f32x4 acc2[2][4],
                                         const float* __restrict__ bias, int w, int lane){
#pragma unroll
  for (int i=0;i<4;++i){
    float bv = bias[w*64 + i*16 + (lane&15)];
    f32x4 b4 = {bv,bv,bv,bv};
    f32x4 z4 = {0.f,0.f,0.f,0.f};
    acc[0][i]=b4; acc[1][i]=b4;
    acc2[0][i]=z4; acc2[1][i]=z4;
  }
}

__device__ __forceinline__ void finish_acc(f32x4 acc[2][4], f32x4 acc2[2][4]){
#pragma unroll
  for (int mt=0;mt<2;++mt)
#pragma unroll
    for (int i=0;i<4;++i)
      acc[mt][i] += acc2[mt][i]*LO_INV;
}

// gates[32 rows][512 cols] += [A1|A2]_split * W  (3-product fp16 split)
template<int KT, int SPLIT>
__device__ __forceinline__ void gemm_gates(f32x4 acc[2][4], f32x4 acc2[2][4],
    const f16x8* __restrict__ Bp,
    const f16* __restrict__ A1h, const f16* __restrict__ A1l,
    const f16* __restrict__ A2h, const f16* __restrict__ A2l,
    int w, int lane)
{
  const int nbase = w*4;
  f16x8 B[3][8];
  f16x8 A[2][4];
  load_b4(B[0], Bp, 0, nbase, lane);
  if (KT > 1) load_b4(B[1], Bp, 1, nbase, lane);
  load_a4<SPLIT>(A[0], A1h,A1l,A2h,A2l, 0, lane);
#pragma unroll
  for (int kt=0; kt<KT; ++kt){
    if (kt+2 < KT) load_b4(B[(kt+2)%3], Bp, kt+2, nbase, lane);
    if (kt+1 < KT) load_a4<SPLIT>(A[(kt+1)%2], A1h,A1l,A2h,A2l, kt+1, lane);
    const f16x8* Bc = B[kt%3];
    const f16x8* Ac = A[kt%2];
#pragma unroll
    for (int i=0;i<4;++i){                       // hi*hi -> acc
      acc[0][i] = MFMA16(Ac[0], Bc[2*i], acc[0][i]);
      acc[1][i] = MFMA16(Ac[2], Bc[2*i], acc[1][i]);
    }
#pragma unroll
    for (int i=0;i<4;++i){                       // hi*lo' -> acc2
      acc2[0][i] = MFMA16(Ac[0], Bc[2*i+1], acc2[0][i]);
      acc2[1][i] = MFMA16(Ac[2], Bc[2*i+1], acc2[1][i]);
    }
#pragma unroll
    for (int i=0;i<4;++i){                       // lo'*hi -> acc2
      acc2[0][i] = MFMA16(Ac[1], Bc[2*i], acc2[0][i]);
      acc2[1][i] = MFMA16(Ac[3], Bc[2*i], acc2[1][i]);
    }
  }
}

// 4x4 transpose within a lane-quad: in = own gate column (4 rows),
// out = a_r holds gate r for row (lane&3).
__device__ __forceinline__ void quad_transpose(float&a0,float&a1,float&a2,float&a3,int q){
  bool odd = (q & 1) != 0;
  float s0 = odd ? a0 : a1, s1 = odd ? a2 : a3;
  float r0 = __shfl_xor(s0,1), r1 = __shfl_xor(s1,1);
  float b0 = odd ? r0 : a0, b1 = odd ? a1 : r0;
  float b2 = odd ? r1 : a2, b3 = odd ? a3 : r1;
  bool hi = (q & 2) != 0;
  float u0 = hi ? b0 : b2, u1 = hi ? b1 : b3;
  float v0 = __shfl_xor(u0,2), v1 = __shfl_xor(u1,2);
  a0 = hi ? v0 : b0; a1 = hi ? v1 : b1;
  a2 = hi ? b2 : v0; a3 = hi ? b3 : v1;
}

template<int DSTRIDE>
__device__ __forceinline__ void lstm_update_m(f32x4 acc[2][4], float cr[2][4],
    f16* __restrict__ Dh, f16* __restrict__ Dl, int w, int lane)
{
  const int q = lane & 3;
  const int rsub = ((lane>>4)<<2) + q;
  const int usub = w*16 + ((lane&15)>>2);
#pragma unroll
  for (int mt=0;mt<2;++mt)
#pragma unroll
  for (int nt=0;nt<4;++nt){
    float a0=acc[mt][nt][0], a1=acc[mt][nt][1], a2=acc[mt][nt][2], a3=acc[mt][nt][3];
    quad_transpose(a0,a1,a2,a3,q);
    float iv=fsig(a0), fv=fsig(a1), gv=ftanh(a2), ov=fsig(a3);
    float cn = fv*cr[mt][nt] + iv*gv;
    cr[mt][nt] = cn;
    float h = ov*ftanh(cn);
    f16 hh = (f16)h;
    f16 hl = (f16)((h - (float)hh)*LO_SCALE);
    int off = (mt*16 + rsub)*DSTRIDE + usub + nt*4;
    Dh[off]=hh; Dl[off]=hl;
  }
}

__global__ void __launch_bounds__(512, 2)
lstm_main(const float* __restrict__ hist, const float* __restrict__ ws,
          float* __restrict__ out)
{
  const f16* wh = (const f16*)ws;
  const float* wf = ws + FOFF;
  const f16x8* BE0 = (const f16x8*)(wh + HOFF_E0);
  const f16x8* BE1 = (const f16x8*)(wh + HOFF_E1);
  const f16x8* BD0 = (const f16x8*)(wh + HOFF_D0);
  const f16x8* BD1 = (const f16x8*)(wh + HOFF_D1);
  const f16x8* BH  = (const f16x8*)(wh + HOFF_H);

  __shared__ __align__(16) f16 A1h[32*A1S], A1l[32*A1S];
  __shared__ __align__(16) f16 A2h[32*A2S], A2l[32*A2S];
  __shared__ __align__(16) float o1[32*132];

  const int tid  = threadIdx.x;
  const int w    = tid >> 6;
  const int lane = tid & 63;
  const int b0   = blockIdx.x * 32;

  for (int i = tid; i < 32*A1S; i += 512){ A1h[i]=(f16)0.f; A1l[i]=(f16)0.f; }
  for (int i = tid; i < 32*A2S; i += 512){ A2h[i]=(f16)0.f; A2l[i]=(f16)0.f; }
  float c0r[2][4] = {{0,0,0,0},{0,0,0,0}};
  float c1r[2][4] = {{0,0,0,0},{0,0,0,0}};
  f32x4 acc[2][4], acc2[2][4];
  __syncthreads();

  // ------------------------- encoder: 128 steps ---------------------------
  for (int t=0; t<128; ++t){
    if (tid < 192){
      int r = tid/6, d = tid - r*6;
      float v = hist[(b0+r)*768 + t*6 + d];
      f16 hv = (f16)v;
      A1h[r*A1S + 128 + d] = hv;
      A1l[r*A1S + 128 + d] = (f16)((v - (float)hv)*LO_SCALE);
    }
    __syncthreads();

    init_acc(acc, acc2, wf + FB_E0, w, lane);
    gemm_gates<5,99>(acc, acc2, BE0, A1h, A1l, A2h, A2l, w, lane);
    finish_acc(acc, acc2);
    __syncthreads();
    lstm_update_m<A1S>(acc, c0r, A1h, A1l, w, lane);   // h0 -> A1[0..127]
    __syncthreads();

    init_acc(acc, acc2, wf + FB_E1, w, lane);
    gemm_gates<8,4>(acc, acc2, BE1, A1h, A1l, A2h, A2l, w, lane);
    finish_acc(acc, acc2);
    __syncthreads();
    lstm_update_m<A2S>(acc, c1r, A2h, A2l, w, lane);   // h1 -> A2[0..127]
    __syncthreads();
  }

  // decoder seed: x = hist[:, -1, :2]; zero enc-only x cols 130..133
  if (tid < 64){
    int r = tid>>1, j = tid&1;
    float v = hist[(b0+r)*768 + 762 + j];
    f16 hv = (f16)v;
    A1h[r*A1S + 128 + j] = hv;
    A1l[r*A1S + 128 + j] = (f16)((v - (float)hv)*LO_SCALE);
  } else if (tid < 192){
    int idx = tid - 64;
    int r = idx>>2, cl = 130 + (idx&3);
    A1h[r*A1S + cl] = (f16)0.f;
    A1l[r*A1S + cl] = (f16)0.f;
  }
  __syncthreads();

  // ------------------------- decoder: 125 steps ---------------------------
  for (int t=0; t<125; ++t){
    init_acc(acc, acc2, wf + FB_D0, w, lane);
    gemm_gates<5,99>(acc, acc2, BD0, A1h, A1l, A2h, A2l, w, lane);
    finish_acc(acc, acc2);
    __syncthreads();
    lstm_update_m<A1S>(acc, c0r, A1h, A1l, w, lane);
    __syncthreads();

    init_acc(acc, acc2, wf + FB_D1, w, lane);
    gemm_gates<8,4>(acc, acc2, BD1, A1h, A1l, A2h, A2l, w, lane);
    finish_acc(acc, acc2);
    __syncthreads();
    lstm_update_m<A2S>(acc, c1r, A2h, A2l, w, lane);
    __syncthreads();

    // head layer 1: relu(h1 @ W1^T + b1) -> o1 (fp32 LDS)
    {
      f32x4 ha[2], ha2[2];
      float bv = wf[FB_H1 + w*16 + (lane&15)];
      ha[0] = (f32x4){bv,bv,bv,bv}; ha[1] = ha[0];
      ha2[0] = (f32x4){0.f,0.f,0.f,0.f}; ha2[1] = ha2[0];
      f16x8 hb[4][2];
#pragma unroll
      for (int kt=0;kt<4;++kt){
        int base = ((kt*8 + w)*2)*64 + lane;
        hb[kt][0] = BH[base];
        hb[kt][1] = BH[base+64];
      }
#pragma unroll
      for (int kt=0;kt<4;++kt){
        int kc = kt*32;
        f16x8 a0h = load_afrag<A2S>(A2h,0,kc,lane);
        f16x8 a0l = load_afrag<A2S>(A2l,0,kc,lane);
        f16x8 a1h = load_afrag<A2S>(A2h,1,kc,lane);
        f16x8 a1l = load_afrag<A2S>(A2l,1,kc,lane);
        ha[0]  = MFMA16(a0h, hb[kt][0], ha[0]);
        ha[1]  = MFMA16(a1h, hb[kt][0], ha[1]);
        ha2[0] = MFMA16(a0h, hb[kt][1], ha2[0]);
        ha2[1] = MFMA16(a1h, hb[kt][1], ha2[1]);
        ha2[0] = MFMA16(a0l, hb[kt][0], ha2[0]);
        ha2[1] = MFMA16(a1l, hb[kt][0], ha2[1]);
      }
#pragma unroll
      for (int mt=0;mt<2;++mt)
#pragma unroll
      for (int r=0;r<4;++r){
        float v = ha[mt][r] + ha2[mt][r]*LO_INV;
        v = v > 0.f ? v : 0.f;
        o1[(mt*16 + ((lane>>4)<<2) + r)*132 + w*16 + (lane&15)] = v;
      }
    }
    __syncthreads();

    // head layer 2 + autoregressive feedback
    if (tid < 64){
      int r = tid>>1, j = tid&1;
      const float* op = o1 + r*132;
      const float* w2 = wf + FB_W2 + j;
      float s0=0.f,s1=0.f,s2=0.f,s3=0.f;
#pragma unroll
      for (int k=0;k<128;k+=4){
        s0 = fmaf(op[k],   w2[2*k],   s0);
        s1 = fmaf(op[k+1], w2[2*k+2], s1);
        s2 = fmaf(op[k+2], w2[2*k+4], s2);
        s3 = fmaf(op[k+3], w2[2*k+6], s3);
      }
      float pred = wf[FB_B2 + j] + ((s0+s1)+(s2+s3));
      out[(b0+r)*250 + t*2 + j] = pred;
      f16 ph = (f16)pred;
      A1h[r*A1S + 128 + j] = ph;
      A1l[r*A1S + 128 + j] = (f16)((pred - (float)ph)*LO_SCALE);
    }
    __syncthreads();
  }
}

// ---------------------------------------------------------------------------
// setup: pack weights into per-lane MFMA fragment order (hi/lo fp16 planes,
// lo prescaled x2048), biases fused + col-remapped, W2 transposed.
// col = unit*4 + gate; orig gate-major row = gate*128 + unit.
// k element (lane,j): k = kt*32 + (j>=4?16:0) + (lane>>4)*4 + (j&3)
// ---------------------------------------------------------------------------
__global__ void setup_kernel(
    const float* __restrict__ eWih0, const float* __restrict__ eWhh0,
    const float* __restrict__ ebih0, const float* __restrict__ ebhh0,
    const float* __restrict__ eWih1, const float* __restrict__ eWhh1,
    const float* __restrict__ ebih1, const float* __restrict__ ebhh1,
    const float* __restrict__ dWih0, const float* __restrict__ dWhh0,
    const float* __restrict__ dbih0, const float* __restrict__ dbhh0,
    const float* __restrict__ dWih1, const float* __restrict__ dWhh1,
    const float* __restrict__ dbih1, const float* __restrict__ dbhh1,
    const float* __restrict__ W1, const float* __restrict__ b1,
    const float* __restrict__ W2, const float* __restrict__ b2,
    float* __restrict__ ws)
{
  int i = blockIdx.x*256 + threadIdx.x;
  if (i < H_TOTAL){
    f16* whp = (f16*)ws;
    const float *Wa, *Wb; int ka, kb, off; bool head = false;
    if      (i < HOFF_E1){ off=HOFF_E0; Wa=eWhh0; ka=128; Wb=eWih0; kb=6; }
    else if (i < HOFF_D0){ off=HOFF_E1; Wa=eWih1; ka=128; Wb=eWhh1; kb=128; }
    else if (i < HOFF_D1){ off=HOFF_D0; Wa=dWhh0; ka=128; Wb=dWih0; kb=2; }
    else if (i < HOFF_H) { off=HOFF_D1; Wa=dWih1; ka=128; Wb=dWhh1; kb=128; }
    else                 { off=HOFF_H;  Wa=W1; ka=128; Wb=W1; kb=0; head=true; }
    int local = i - off;
    int j     = local & 7;
    int lane  = (local>>3) & 63;
    int plane = (local>>9) & 1;
    int nk    = local >> 10;
    int NTl   = head ? 8 : 32;
    int n     = nk % NTl;
    int kt    = nk / NTl;
    int col   = n*16 + (lane&15);
    int koff  = ((j>>2)<<4) + ((lane>>4)<<2) + (j&3);
    int kin   = kt*32 + koff;
    float val;
    if (head){
      val = (kin < 128) ? W1[col*128 + kin] : 0.f;
    } else {
      int orow = (col&3)*128 + (col>>2);
      val = (kin < ka) ? Wa[orow*ka + kin]
          : ((kin < ka+kb) ? Wb[orow*kb + (kin-ka)] : 0.f);
    }
    f16 hi = (f16)val;
    if (plane == 0) whp[i] = hi;
    else            whp[i] = (f16)((val - (float)hi)*LO_SCALE);
  } else if (i < H_TOTAL + F_TOTAL){
    int f = i - H_TOTAL;
    float* wfp = ws + FOFF;
    if (f < 2048){
      int layer = f >> 9, c = f & 511;
      int orow = (c&3)*128 + (c>>2);
      const float *bi, *bh;
      if      (layer==0){ bi=ebih0; bh=ebhh0; }
      else if (layer==1){ bi=ebih1; bh=ebhh1; }
      else if (layer==2){ bi=dbih0; bh=dbhh0; }
      else              { bi=dbih1; bh=dbhh1; }
      wfp[f] = bi[orow] + bh[orow];
    } else if (f < 2176){
      wfp[f] = b1[f-2048];
    } else if (f < 2432){
      int k = (f-2176)>>1, j = (f-2176)&1;
      wfp[f] = W2[j*128 + k];
    } else {
      wfp[f] = b2[f-2432];
    }
  }
}

extern "C" void kernel_launch(void* const* d_in, const int* in_sizes, int n_in,
                              void* d_out, int out_size, void* d_ws, size_t ws_size,
                              hipStream_t stream)
{
  const float* hist = (const float*)d_in[0];
  float* ws = (float*)d_ws;

  int total = H_TOTAL + F_TOTAL;
  setup_kernel<<<(total + 255)/256, 256, 0, stream>>>(
      (const float*)d_in[1],  (const float*)d_in[2],
      (const float*)d_in[3],  (const float*)d_in[4],
      (const float*)d_in[5],  (const float*)d_in[6],
      (const float*)d_in[7],  (const float*)d_in[8],
      (const float*)d_in[9],  (const float*)d_in[10],
      (const float*)d_in[11], (const float*)d_in[12],
      (const float*)d_in[13], (const float*)d_in[14],
      (const float*)d_in[15], (const float*)d_in[16],
      (const float*)d_in[17], (const float*)d_in[18],
      (const float*)d_in[19], (const float*)d_in[20],
      ws);

  lstm_main<<<256, 512, 0, stream>>>(hist, ws, (float*)d_out);
}

// Round 3
// 9466.822 us; speedup vs baseline: 2.5275x; 1.0808x over previous
//
#include <hip/hip_runtime.h>

// ---------------------------------------------------------------------------
// LSTM autoregressive, MI355X. Round 3: fp16 hi/lo split MFMA (16x16x32_f16)
// + nontemporal hist/out (L2 pollution control), cross-barrier B-tile
// prefetch, barrier elision, LDS bank-conflict padding.
// B=8192, BM=32 rows/block, 256 blocks, 512 threads (8 waves).
// ---------------------------------------------------------------------------

typedef _Float16 f16;
typedef _Float16 f16x4 __attribute__((ext_vector_type(4)));
typedef _Float16 f16x8 __attribute__((ext_vector_type(8)));
typedef float    f32x4 __attribute__((ext_vector_type(4)));

#define MFMA16(a,b,c) __builtin_amdgcn_mfma_f32_16x16x32_f16((a),(b),(c),0,0,0)

// ws layout: fp16 fragment region (halves), then fp32 region (floats)
#define HOFF_E0 0        // enc L0: KT=5  (k: [Whh 128 | Wih 6 | pad])
#define HOFF_E1 163840   // enc L1: KT=8  (k: [Wih 128 | Whh 128])
#define HOFF_D0 425984   // dec L0: KT=5  (k: [Whh 128 | Wih 2 | pad])
#define HOFF_D1 589824   // dec L1: KT=8
#define HOFF_H  851968   // head W1: KT=4, NT=8
#define H_TOTAL 884736
#define FOFF    442368   // float offset of fp32 region (= H_TOTAL/2)
#define FB_E0 0
#define FB_E1 512
#define FB_D0 1024
#define FB_D1 1536
#define FB_H1 2048
#define FB_W2 2176
#define FB_B2 2432
#define F_TOTAL 2434

#define LO_SCALE 2048.0f
#define LO_INV   (1.0f/2048.0f)

#define A1S 172   // A1 row stride (halves): 160 k + pad; 86 dw/row, 22r%32 bijective
#define A2S 140   // A2 row stride (halves): 128 k + pad; 70 dw/row,  6r%32 bijective
#define O1S 133   // o1 row stride (floats)

__device__ __forceinline__ float fsig(float x){ return 1.0f/(1.0f+__expf(-x)); }
__device__ __forceinline__ float ftanh(float x){
  float a = fabsf(x);
  float e = __expf(-2.0f*a);
  float t = (1.0f-e)/(1.0f+e);
  return x < 0.0f ? -t : t;
}

// A fragment: row = mt*16 + (lane&15); k = kc + (lane>>4)*4 + j (+16 for j>=4)
template<int STRIDE>
__device__ __forceinline__ f16x8 load_afrag(const f16* buf, int mt, int kc, int lane){
  const f16* p = buf + (mt*16 + (lane&15))*STRIDE + kc + ((lane>>4)<<2);
  f16x4 lo = *(const f16x4*)p;
  f16x4 hi = *(const f16x4*)(p+16);
  return __builtin_shufflevector(lo, hi, 0,1,2,3,4,5,6,7);
}

// B fragments for 4 ntiles x {hi,lo}: one dwordx4 per lane per (tile,plane)
__device__ __forceinline__ void load_b4(f16x8* dst, const f16x8* __restrict__ Bp,
                                        int kt, int nbase, int lane){
#pragma unroll
  for (int i=0;i<4;++i){
    int base = ((kt*32 + nbase + i)*2)*64 + lane;
    dst[2*i]   = Bp[base];        // hi plane
    dst[2*i+1] = Bp[base+64];     // lo plane (prescaled x2048)
  }
}

template<int SPLIT>
__device__ __forceinline__ void load_a4(f16x8* dst, const f16* A1h, const f16* A1l,
                                        const f16* A2h, const f16* A2l, int kt, int lane){
  if (kt < SPLIT){
    int kc = kt*32;
    dst[0]=load_afrag<A1S>(A1h,0,kc,lane);
    dst[1]=load_afrag<A1S>(A1l,0,kc,lane);
    dst[2]=load_afrag<A1S>(A1h,1,kc,lane);
    dst[3]=load_afrag<A1S>(A1l,1,kc,lane);
  } else {
    int kc = (kt-SPLIT)*32;
    dst[0]=load_afrag<A2S>(A2h,0,kc,lane);
    dst[1]=load_afrag<A2S>(A2l,0,kc,lane);
    dst[2]=load_afrag<A2S>(A2h,1,kc,lane);
    dst[3]=load_afrag<A2S>(A2l,1,kc,lane);
  }
}

__device__ __forceinline__ void init_acc(f32x4 acc[2][4], f32x4 acc2[2][4],
                                         const float* __restrict__ bias, int w, int lane){
#pragma unroll
  for (int i=0;i<4;++i){
    float bv = bias[w*64 + i*16 + (lane&15)];
    f32x4 b4 = {bv,bv,bv,bv};
    f32x4 z4 = {0.f,0.f,0.f,0.f};
    acc[0][i]=b4; acc[1][i]=b4;
    acc2[0][i]=z4; acc2[1][i]=z4;
  }
}

__device__ __forceinline__ void finish_acc(f32x4 acc[2][4], f32x4 acc2[2][4]){
#pragma unroll
  for (int mt=0;mt<2;++mt)
#pragma unroll
    for (int i=0;i<4;++i)
      acc[mt][i] += acc2[mt][i]*LO_INV;
}

// gates[32 rows][512 cols] += [A1|A2]_split * W  (3-product fp16 split)
// Tile 0 of B arrives preloaded in `pre` (issued before the preceding barriers).
template<int KT, int SPLIT>
__device__ __forceinline__ void gemm_gates(f32x4 acc[2][4], f32x4 acc2[2][4],
    const f16x8* __restrict__ Bp, const f16x8* __restrict__ pre,
    const f16* __restrict__ A1h, const f16* __restrict__ A1l,
    const f16* __restrict__ A2h, const f16* __restrict__ A2l,
    int w, int lane)
{
  const int nbase = w*4;
  f16x8 B[3][8];
  f16x8 A[2][4];
#pragma unroll
  for (int i=0;i<8;++i) B[0][i] = pre[i];
  if (KT > 1) load_b4(B[1], Bp, 1, nbase, lane);
  load_a4<SPLIT>(A[0], A1h,A1l,A2h,A2l, 0, lane);
#pragma unroll
  for (int kt=0; kt<KT; ++kt){
    if (kt+2 < KT) load_b4(B[(kt+2)%3], Bp, kt+2, nbase, lane);
    if (kt+1 < KT) load_a4<SPLIT>(A[(kt+1)%2], A1h,A1l,A2h,A2l, kt+1, lane);
    const f16x8* Bc = B[kt%3];
    const f16x8* Ac = A[kt%2];
#pragma unroll
    for (int i=0;i<4;++i){                       // hi*hi -> acc
      acc[0][i] = MFMA16(Ac[0], Bc[2*i], acc[0][i]);
      acc[1][i] = MFMA16(Ac[2], Bc[2*i], acc[1][i]);
    }
#pragma unroll
    for (int i=0;i<4;++i){                       // hi*lo' -> acc2
      acc2[0][i] = MFMA16(Ac[0], Bc[2*i+1], acc2[0][i]);
      acc2[1][i] = MFMA16(Ac[2], Bc[2*i+1], acc2[1][i]);
    }
#pragma unroll
    for (int i=0;i<4;++i){                       // lo'*hi -> acc2
      acc2[0][i] = MFMA16(Ac[1], Bc[2*i], acc2[0][i]);
      acc2[1][i] = MFMA16(Ac[3], Bc[2*i], acc2[1][i]);
    }
  }
}

// 4x4 transpose within a lane-quad: in = own gate column (4 rows),
// out = a_r holds gate r for row (lane&3).
__device__ __forceinline__ void quad_transpose(float&a0,float&a1,float&a2,float&a3,int q){
  bool odd = (q & 1) != 0;
  float s0 = odd ? a0 : a1, s1 = odd ? a2 : a3;
  float r0 = __shfl_xor(s0,1), r1 = __shfl_xor(s1,1);
  float b0 = odd ? r0 : a0, b1 = odd ? a1 : r0;
  float b2 = odd ? r1 : a2, b3 = odd ? a3 : r1;
  bool hi = (q & 2) != 0;
  float u0 = hi ? b0 : b2, u1 = hi ? b1 : b3;
  float v0 = __shfl_xor(u0,2), v1 = __shfl_xor(u1,2);
  a0 = hi ? v0 : b0; a1 = hi ? v1 : b1;
  a2 = hi ? b2 : v0; a3 = hi ? b3 : v1;
}

template<int DSTRIDE>
__device__ __forceinline__ void lstm_update_m(f32x4 acc[2][4], float cr[2][4],
    f16* __restrict__ Dh, f16* __restrict__ Dl, int w, int lane)
{
  const int q = lane & 3;
  const int rsub = ((lane>>4)<<2) + q;
  const int usub = w*16 + ((lane&15)>>2);
#pragma unroll
  for (int mt=0;mt<2;++mt)
#pragma unroll
  for (int nt=0;nt<4;++nt){
    float a0=acc[mt][nt][0], a1=acc[mt][nt][1], a2=acc[mt][nt][2], a3=acc[mt][nt][3];
    quad_transpose(a0,a1,a2,a3,q);
    float iv=fsig(a0), fv=fsig(a1), gv=ftanh(a2), ov=fsig(a3);
    float cn = fv*cr[mt][nt] + iv*gv;
    cr[mt][nt] = cn;
    float h = ov*ftanh(cn);
    f16 hh = (f16)h;
    f16 hl = (f16)((h - (float)hh)*LO_SCALE);
    int off = (mt*16 + rsub)*DSTRIDE + usub + nt*4;
    Dh[off]=hh; Dl[off]=hl;
  }
}

__global__ void __launch_bounds__(512, 2)
lstm_main(const float* __restrict__ hist, const float* __restrict__ ws,
          float* __restrict__ out)
{
  const f16* wh = (const f16*)ws;
  const float* wf = ws + FOFF;
  const f16x8* BE0 = (const f16x8*)(wh + HOFF_E0);
  const f16x8* BE1 = (const f16x8*)(wh + HOFF_E1);
  const f16x8* BD0 = (const f16x8*)(wh + HOFF_D0);
  const f16x8* BD1 = (const f16x8*)(wh + HOFF_D1);
  const f16x8* BH  = (const f16x8*)(wh + HOFF_H);

  __shared__ __align__(16) f16 A1h[32*A1S], A1l[32*A1S];
  __shared__ __align__(16) f16 A2h[32*A2S], A2l[32*A2S];
  __shared__ __align__(16) float o1[32*O1S];

  const int tid  = threadIdx.x;
  const int w    = tid >> 6;
  const int lane = tid & 63;
  const int b0   = blockIdx.x * 32;
  const int nbase = w*4;

  for (int i = tid; i < 32*A1S; i += 512){ A1h[i]=(f16)0.f; A1l[i]=(f16)0.f; }
  for (int i = tid; i < 32*A2S; i += 512){ A2h[i]=(f16)0.f; A2l[i]=(f16)0.f; }
  float c0r[2][4] = {{0,0,0,0},{0,0,0,0}};
  float c1r[2][4] = {{0,0,0,0},{0,0,0,0}};
  f32x4 acc[2][4], acc2[2][4];
  f16x8 p0[8], p1[8];

  const int lr = tid/6, ld = tid - (tid/6)*6;   // hist loader (tid<192)

  // t=0 hist load + first E0 tile prefetch
  if (tid < 192){
    float v = __builtin_nontemporal_load(&hist[(b0+lr)*768 + ld]);
    f16 hv = (f16)v;
    A1h[lr*A1S + 128 + ld] = hv;
    A1l[lr*A1S + 128 + ld] = (f16)((v - (float)hv)*LO_SCALE);
  }
  load_b4(p0, BE0, 0, nbase, lane);
  __syncthreads();

  // ------------------------- encoder: 128 steps ---------------------------
  for (int t=0; t<128; ++t){
    init_acc(acc, acc2, wf + FB_E0, w, lane);
    gemm_gates<5,99>(acc, acc2, BE0, p0, A1h, A1l, A2h, A2l, w, lane);
    load_b4(p1, BE1, 0, nbase, lane);            // preissue E1 tile0
    finish_acc(acc, acc2);
    __syncthreads();
    lstm_update_m<A1S>(acc, c0r, A1h, A1l, w, lane);   // h0 -> A1[0..127]
    __syncthreads();

    init_acc(acc, acc2, wf + FB_E1, w, lane);
    gemm_gates<8,4>(acc, acc2, BE1, p1, A1h, A1l, A2h, A2l, w, lane);
    load_b4(p0, BE0, 0, nbase, lane);            // preissue next-step E0 tile0
    if (t < 127 && tid < 192){                   // hist(t+1): x-cols idle here
      float v = __builtin_nontemporal_load(&hist[(b0+lr)*768 + (t+1)*6 + ld]);
      f16 hv = (f16)v;
      A1h[lr*A1S + 128 + ld] = hv;
      A1l[lr*A1S + 128 + ld] = (f16)((v - (float)hv)*LO_SCALE);
    }
    finish_acc(acc, acc2);
    __syncthreads();
    lstm_update_m<A2S>(acc, c1r, A2h, A2l, w, lane);   // h1 -> A2[0..127]
    __syncthreads();
  }

  // decoder seed: x = hist[:, -1, :2]; zero enc-only x cols 130..133
  if (tid < 64){
    int r = tid>>1, j = tid&1;
    float v = __builtin_nontemporal_load(&hist[(b0+r)*768 + 762 + j]);
    f16 hv = (f16)v;
    A1h[r*A1S + 128 + j] = hv;
    A1l[r*A1S + 128 + j] = (f16)((v - (float)hv)*LO_SCALE);
  } else if (tid < 192){
    int idx = tid - 64;
    int r = idx>>2, cl = 130 + (idx&3);
    A1h[r*A1S + cl] = (f16)0.f;
    A1l[r*A1S + cl] = (f16)0.f;
  }
  load_b4(p0, BD0, 0, nbase, lane);
  __syncthreads();

  // ------------------------- decoder: 125 steps ---------------------------
  for (int t=0; t<125; ++t){
    init_acc(acc, acc2, wf + FB_D0, w, lane);
    gemm_gates<5,99>(acc, acc2, BD0, p0, A1h, A1l, A2h, A2l, w, lane);
    load_b4(p1, BD1, 0, nbase, lane);            // preissue D1 tile0
    finish_acc(acc, acc2);
    __syncthreads();
    lstm_update_m<A1S>(acc, c0r, A1h, A1l, w, lane);
    __syncthreads();

    init_acc(acc, acc2, wf + FB_D1, w, lane);
    gemm_gates<8,4>(acc, acc2, BD1, p1, A1h, A1l, A2h, A2l, w, lane);
    load_b4(p0, BD0, 0, nbase, lane);            // preissue next-step D0 tile0
    finish_acc(acc, acc2);
    __syncthreads();
    lstm_update_m<A2S>(acc, c1r, A2h, A2l, w, lane);
    __syncthreads();

    // head layer 1: relu(h1 @ W1^T + b1) -> o1 (fp32 LDS)
    {
      f32x4 ha[2], ha2[2];
      float bv = wf[FB_H1 + w*16 + (lane&15)];
      ha[0] = (f32x4){bv,bv,bv,bv}; ha[1] = ha[0];
      ha2[0] = (f32x4){0.f,0.f,0.f,0.f}; ha2[1] = ha2[0];
      f16x8 hb[4][2];
#pragma unroll
      for (int kt=0;kt<4;++kt){
        int base = ((kt*8 + w)*2)*64 + lane;
        hb[kt][0] = BH[base];
        hb[kt][1] = BH[base+64];
      }
#pragma unroll
      for (int kt=0;kt<4;++kt){
        int kc = kt*32;
        f16x8 a0h = load_afrag<A2S>(A2h,0,kc,lane);
        f16x8 a0l = load_afrag<A2S>(A2l,0,kc,lane);
        f16x8 a1h = load_afrag<A2S>(A2h,1,kc,lane);
        f16x8 a1l = load_afrag<A2S>(A2l,1,kc,lane);
        ha[0]  = MFMA16(a0h, hb[kt][0], ha[0]);
        ha[1]  = MFMA16(a1h, hb[kt][0], ha[1]);
        ha2[0] = MFMA16(a0h, hb[kt][1], ha2[0]);
        ha2[1] = MFMA16(a1h, hb[kt][1], ha2[1]);
        ha2[0] = MFMA16(a0l, hb[kt][0], ha2[0]);
        ha2[1] = MFMA16(a1l, hb[kt][0], ha2[1]);
      }
#pragma unroll
      for (int mt=0;mt<2;++mt)
#pragma unroll
      for (int r=0;r<4;++r){
        float v = ha[mt][r] + ha2[mt][r]*LO_INV;
        v = v > 0.f ? v : 0.f;
        o1[(mt*16 + ((lane>>4)<<2) + r)*O1S + w*16 + (lane&15)] = v;
      }
    }
    __syncthreads();

    // head layer 2 + autoregressive feedback
    if (tid < 64){
      int r = tid>>1, j = tid&1;
      const float* op = o1 + r*O1S;
      const float* w2 = wf + FB_W2 + j;
      float s0=0.f,s1=0.f,s2=0.f,s3=0.f;
#pragma unroll
      for (int k=0;k<128;k+=4){
        s0 = fmaf(op[k],   w2[2*k],   s0);
        s1 = fmaf(op[k+1], w2[2*k+2], s1);
        s2 = fmaf(op[k+2], w2[2*k+4], s2);
        s3 = fmaf(op[k+3], w2[2*k+6], s3);
      }
      float pred = wf[FB_B2 + j] + ((s0+s1)+(s2+s3));
      __builtin_nontemporal_store(pred, &out[(b0+r)*250 + t*2 + j]);
      f16 ph = (f16)pred;
      A1h[r*A1S + 128 + j] = ph;
      A1l[r*A1S + 128 + j] = (f16)((pred - (float)ph)*LO_SCALE);
    }
    __syncthreads();
  }
}

// ---------------------------------------------------------------------------
// setup: pack weights into per-lane MFMA fragment order (hi/lo fp16 planes,
// lo prescaled x2048), biases fused + col-remapped, W2 transposed.
// col = unit*4 + gate; orig gate-major row = gate*128 + unit.
// k element (lane,j): k = kt*32 + (j>=4?16:0) + (lane>>4)*4 + (j&3)
// ---------------------------------------------------------------------------
__global__ void setup_kernel(
    const float* __restrict__ eWih0, const float* __restrict__ eWhh0,
    const float* __restrict__ ebih0, const float* __restrict__ ebhh0,
    const float* __restrict__ eWih1, const float* __restrict__ eWhh1,
    const float* __restrict__ ebih1, const float* __restrict__ ebhh1,
    const float* __restrict__ dWih0, const float* __restrict__ dWhh0,
    const float* __restrict__ dbih0, const float* __restrict__ dbhh0,
    const float* __restrict__ dWih1, const float* __restrict__ dWhh1,
    const float* __restrict__ dbih1, const float* __restrict__ dbhh1,
    const float* __restrict__ W1, const float* __restrict__ b1,
    const float* __restrict__ W2, const float* __restrict__ b2,
    float* __restrict__ ws)
{
  int i = blockIdx.x*256 + threadIdx.x;
  if (i < H_TOTAL){
    f16* whp = (f16*)ws;
    const float *Wa, *Wb; int ka, kb, off; bool head = false;
    if      (i < HOFF_E1){ off=HOFF_E0; Wa=eWhh0; ka=128; Wb=eWih0; kb=6; }
    else if (i < HOFF_D0){ off=HOFF_E1; Wa=eWih1; ka=128; Wb=eWhh1; kb=128; }
    else if (i < HOFF_D1){ off=HOFF_D0; Wa=dWhh0; ka=128; Wb=dWih0; kb=2; }
    else if (i < HOFF_H) { off=HOFF_D1; Wa=dWih1; ka=128; Wb=dWhh1; kb=128; }
    else                 { off=HOFF_H;  Wa=W1; ka=128; Wb=W1; kb=0; head=true; }
    int local = i - off;
    int j     = local & 7;
    int lane  = (local>>3) & 63;
    int plane = (local>>9) & 1;
    int nk    = local >> 10;
    int NTl   = head ? 8 : 32;
    int n     = nk % NTl;
    int kt    = nk / NTl;
    int col   = n*16 + (lane&15);
    int koff  = ((j>>2)<<4) + ((lane>>4)<<2) + (j&3);
    int kin   = kt*32 + koff;
    float val;
    if (head){
      val = (kin < 128) ? W1[col*128 + kin] : 0.f;
    } else {
      int orow = (col&3)*128 + (col>>2);
      val = (kin < ka) ? Wa[orow*ka + kin]
          : ((kin < ka+kb) ? Wb[orow*kb + (kin-ka)] : 0.f);
    }
    f16 hi = (f16)val;
    if (plane == 0) whp[i] = hi;
    else            whp[i] = (f16)((val - (float)hi)*LO_SCALE);
  } else if (i < H_TOTAL + F_TOTAL){
    int f = i - H_TOTAL;
    float* wfp = ws + FOFF;
    if (f < 2048){
      int layer = f >> 9, c = f & 511;
      int orow = (c&3)*128 + (c>>2);
      const float *bi, *bh;
      if      (layer==0){ bi=ebih0; bh=ebhh0; }
      else if (layer==1){ bi=ebih1; bh=ebhh1; }
      else if (layer==2){ bi=dbih0; bh=dbhh0; }
      else              { bi=dbih1; bh=dbhh1; }
      wfp[f] = bi[orow] + bh[orow];
    } else if (f < 2176){
      wfp[f] = b1[f-2048];
    } else if (f < 2432){
      int k = (f-2176)>>1, j = (f-2176)&1;
      wfp[f] = W2[j*128 + k];
    } else {
      wfp[f] = b2[f-2432];
    }
  }
}

extern "C" void kernel_launch(void* const* d_in, const int* in_sizes, int n_in,
                              void* d_out, int out_size, void* d_ws, size_t ws_size,
                              hipStream_t stream)
{
  const float* hist = (const float*)d_in[0];
  float* ws = (float*)d_ws;

  int total = H_TOTAL + F_TOTAL;
  setup_kernel<<<(total + 255)/256, 256, 0, stream>>>(
      (const float*)d_in[1],  (const float*)d_in[2],
      (const float*)d_in[3],  (const float*)d_in[4],
      (const float*)d_in[5],  (const float*)d_in[6],
      (const float*)d_in[7],  (const float*)d_in[8],
      (const float*)d_in[9],  (const float*)d_in[10],
      (const float*)d_in[11], (const float*)d_in[12],
      (const float*)d_in[13], (const float*)d_in[14],
      (const float*)d_in[15], (const float*)d_in[16],
      (const float*)d_in[17], (const float*)d_in[18],
      (const float*)d_in[19], (const float*)d_in[20],
      ws);

  lstm_main<<<256, 512, 0, stream>>>(hist, ws, (float*)d_out);
}